// Round 1
// baseline (289.128 us; speedup 1.0000x reference)
//
#include <hip/hip_runtime.h>
#include <math.h>

#define DET 512
#define NB  16
#define NT  180
#define PI_D 3.14159265358979323846

// ws layout (bytes):
//   [0,    2048) : godd[512] floats   (odd-offset taps, m -> delta = 2m-511)
//   [2048, 4928) : trig float4[180]   (c, -s, K, -8s) with K = 256(s-c)+255.5
//   [8192, +5.9M): xf[NB][NT][DET] floats  (filtered sinogram, (b,t,d) layout)

__global__ __launch_bounds__(512) void setup_kernel(float* __restrict__ ws) {
  int tid = threadIdx.x;
  float*  godd = ws;
  float4* trig = (float4*)(ws + 512);
  if (tid < 512) {
    int o = 2 * tid - 511;            // odd offset in [-511, 511]
    double od = (double)o;
    godd[tid] = (float)(-2.0 / (PI_D * PI_D * od * od));
  }
  if (tid < 180) {
    float rad = (float)tid * (float)(PI_D / 180.0);   // matches f32 arange * f32(pi/180)
    double c = cos((double)rad), s = sin((double)rad);
    float4 t4;
    t4.x = (float)c;
    t4.y = (float)(-s);
    t4.z = (float)(256.0 * (s - c) + 255.5);
    t4.w = (float)(-8.0 * s);
    trig[tid] = t4;
  }
}

// ---------------- Filter: direct conv with register-window taps ----------------
// Block: 256 threads = 8 t-columns x 32 d-strips (16 outputs each).
// xcp row: [0,512)=0 | [512,1024)=x | [1024,1536)=0 ; stride FS for banks.
#define FS 1542

__global__ __launch_bounds__(256) void filter_kernel(const float* __restrict__ x,
                                                     const float* __restrict__ ws,
                                                     float* __restrict__ xf) {
  __shared__ float xcp[8 * FS];
  __shared__ float gl[512];
  int tid = threadIdx.x;
  int b   = blockIdx.y;
  int t0  = blockIdx.x * 8;

  for (int i = tid; i < 512; i += 256) gl[i] = ws[i];
  // zero halos
  for (int i = tid; i < 8 * 1024; i += 256) {
    int tt = i >> 10, q = i & 1023;
    int idx = (q < 512) ? q : q + 512;
    xcp[tt * FS + idx] = 0.f;
  }
  // stage x columns: xcp[tt][512+k] = x[b][k][t0+tt]
  for (int i = tid; i < 8 * 512; i += 256) {
    int k = i >> 3, tt = i & 7;
    int t = t0 + tt;
    float v = (t < NT) ? x[(b * DET + k) * NT + t] : 0.f;
    xcp[tt * FS + 512 + k] = v;
  }
  __syncthreads();

  int tt = tid & 7;
  int d0 = (tid >> 3) * 16;
  const float* row = &xcp[tt * FS];

  float acc[16];
#pragma unroll
  for (int i = 0; i < 16; i++) acc[i] = 0.f;

  for (int m = 0; m < 512; m += 4) {
    float4 g4 = *(const float4*)&gl[m];
    int A0 = d0 + 1016 - 2 * m;       // even -> float2 aligned
    float w[24];
#pragma unroll
    for (int q = 0; q < 12; q++) {
      float2 t2 = *(const float2*)&row[A0 + 2 * q];
      w[2 * q] = t2.x; w[2 * q + 1] = t2.y;
    }
#pragma unroll
    for (int i = 0; i < 16; i++) {
      acc[i] = fmaf(g4.x, w[7 + i], acc[i]);   // tap m   : idx = (d+511) - 2m
      acc[i] = fmaf(g4.y, w[5 + i], acc[i]);   // tap m+1
      acc[i] = fmaf(g4.z, w[3 + i], acc[i]);   // tap m+2
      acc[i] = fmaf(g4.w, w[1 + i], acc[i]);   // tap m+3
    }
  }
  // center tap 0.5 * x[d]
#pragma unroll
  for (int i = 0; i < 16; i++)
    acc[i] = fmaf(0.5f, row[512 + d0 + i], acc[i]);

  int t = t0 + tt;
  if (t < NT) {
    float* dst = &xf[(b * NT + t) * DET + d0];
#pragma unroll
    for (int i = 0; i < 16; i++) dst[i] = acc[i];
  }
}

// ---------------- Backprojection ----------------
// Block: 256 threads, 32x32 pixel tile, 4 pixels/thread (y strided by 8).
// Column of angle t staged into LDS with +-108 zero pad: gather needs no masks.
#define PAD 108
#define COLSZ 728   // 108 + 512 + 108

__global__ __launch_bounds__(256) void backproj_kernel(const float* __restrict__ xf,
                                                       const float* __restrict__ ws,
                                                       float* __restrict__ out) {
  __shared__ float colp[COLSZ];
  __shared__ float4 trig_s[180];
  int tid  = threadIdx.x;
  int b    = blockIdx.y;
  int tile = blockIdx.x;
  int tx = (tile & 15) * 32;
  int ty = (tile >> 4) * 32;

  const float4* trg = (const float4*)(ws + 512);
  if (tid < 180) trig_s[tid] = trg[tid];
  if (tid < PAD) colp[tid] = 0.f;
  if (tid >= 256 - PAD) colp[PAD + DET + (tid - (256 - PAD))] = 0.f;

  int lx  = tid & 31;
  int lyb = tid >> 5;
  float xc = (float)(tx + lx) + 0.5f;
  float yc = (float)(ty + lyb) + 0.5f;
  const float* xfb = &xf[b * NT * DET];

  float accs[4] = {0.f, 0.f, 0.f, 0.f};

  for (int t = 0; t < NT; t++) {
    __syncthreads();
    ((float2*)(colp + PAD))[tid] = ((const float2*)(xfb + t * DET))[tid];
    __syncthreads();
    float4 tr = trig_s[t];
    // iy = c*(x+0.5) - s*(y+0.5) + 256(s-c) + 255.5 ; steps by -8s along j
    float iy = fmaf(tr.y, yc, fmaf(tr.x, xc, tr.z));
#pragma unroll
    for (int j = 0; j < 4; j++) {
      float fl = floorf(iy);
      int   i0 = (int)fl;
      float w1 = iy - fl;
      float g0 = colp[PAD + i0];
      float g1 = colp[PAD + 1 + i0];
      accs[j] = fmaf(1.0f - w1, g0, accs[j]);
      accs[j] = fmaf(w1, g1, accs[j]);
      iy += tr.w;
    }
  }

  const float SC = (float)(PI_D / 360.0);
  int kx = 2 * (tx + lx) + 1 - 512;
  float* ob = &out[(size_t)b * DET * DET];
#pragma unroll
  for (int j = 0; j < 4; j++) {
    int y  = ty + lyb + 8 * j;
    int ky = 2 * y + 1 - 512;
    int r2 = kx * kx + ky * ky;                 // exact: mask <=> u_x^2+u_y^2 <= 511/512
    float v = (r2 <= 261632) ? accs[j] * SC : 0.f;
    ob[y * DET + tx + lx] = v;
  }
}

extern "C" void kernel_launch(void* const* d_in, const int* in_sizes, int n_in,
                              void* d_out, int out_size, void* d_ws, size_t ws_size,
                              hipStream_t stream) {
  const float* x = (const float*)d_in[0];
  float* out = (float*)d_out;
  float* ws  = (float*)d_ws;
  float* xf  = (float*)((char*)d_ws + 8192);

  setup_kernel<<<1, 512, 0, stream>>>(ws);
  filter_kernel<<<dim3(23, 16), 256, 0, stream>>>(x, ws, xf);
  backproj_kernel<<<dim3(256, 16), 256, 0, stream>>>(xf, ws, out);
}

// Round 2
// 219.206 us; speedup vs baseline: 1.3190x; 1.3190x over previous
//
#include <hip/hip_runtime.h>
#include <math.h>

#define DET 512
#define NB  16
#define NT  180
#define PI_D 3.14159265358979323846
#define NPAIR 89
#define PADQ 108
#define QROW 768                 // padded quads per (b,tp) row; 728 used
#define XF_OFF 8192
#define XQ_OFF (XF_OFF + NB*NT*DET*4)

// ws layout (bytes):
//   [0,2048)      godd[512]          odd-tap filter coefficients
//   [2048,2760)   trigp float2[89]   symmetric pair trig (c,s)
//   [XF_OFF,+5.9M)  xf[b][t][d]      filtered sinogram
//   [XQ_OFF,+17.5M) xq[b][tp][768]   float4 quads (gt[i],gu[i],gt[i+1],gu[i+1]), pad +-108

__device__ inline float2 pk_fma2(float2 a, float2 b, float2 c) {
  float2 d;
  asm("v_pk_fma_f32 %0, %1, %2, %3" : "=v"(d) : "v"(a), "v"(b), "v"(c));
  return d;
}

__device__ inline void stage3(const float4* g, char* l) {
#pragma unroll
  for (int c = 0; c < 3; c++)
    __builtin_amdgcn_global_load_lds(
        (const __attribute__((address_space(1))) unsigned int*)(g + c * 256),
        (__attribute__((address_space(3))) unsigned int*)(l + c * 4096),
        16, 0, 0);
}

__global__ __launch_bounds__(512) void setup_kernel(float* __restrict__ ws) {
  int tid = threadIdx.x;
  float*  godd  = ws;
  float2* trigp = (float2*)(ws + 512);
  if (tid < 512) {
    int o = 2 * tid - 511;
    double od = (double)o;
    godd[tid] = (float)(-2.0 / (PI_D * PI_D * od * od));
  }
  if (tid < NPAIR) {
    int t = tid + 1, u = 179 - tid;
    float rt = (float)t * (float)(PI_D / 180.0);
    float ru = (float)u * (float)(PI_D / 180.0);
    double ct = cos((double)rt), st = sin((double)rt);
    double cu = cos((double)ru), su = sin((double)ru);
    float2 cs;
    cs.x = (float)((ct - cu) * 0.5);   // ~ cos(t), with -cos(u) averaged in
    cs.y = (float)((st + su) * 0.5);   // ~ sin(t)
    trigp[tid] = cs;
  }
}

// ---------------- Filter: direct conv (unchanged from R1) ----------------
#define FS 1542

__global__ __launch_bounds__(256) void filter_kernel(const float* __restrict__ x,
                                                     const float* __restrict__ ws,
                                                     float* __restrict__ xf) {
  __shared__ float xcp[8 * FS];
  __shared__ float gl[512];
  int tid = threadIdx.x;
  int b   = blockIdx.y;
  int t0  = blockIdx.x * 8;

  for (int i = tid; i < 512; i += 256) gl[i] = ws[i];
  for (int i = tid; i < 8 * 1024; i += 256) {
    int tt = i >> 10, q = i & 1023;
    int idx = (q < 512) ? q : q + 512;
    xcp[tt * FS + idx] = 0.f;
  }
  for (int i = tid; i < 8 * 512; i += 256) {
    int k = i >> 3, tt = i & 7;
    int t = t0 + tt;
    float v = (t < NT) ? x[(b * DET + k) * NT + t] : 0.f;
    xcp[tt * FS + 512 + k] = v;
  }
  __syncthreads();

  int tt = tid & 7;
  int d0 = (tid >> 3) * 16;
  const float* row = &xcp[tt * FS];

  float acc[16];
#pragma unroll
  for (int i = 0; i < 16; i++) acc[i] = 0.f;

  for (int m = 0; m < 512; m += 4) {
    float4 g4 = *(const float4*)&gl[m];
    int A0 = d0 + 1016 - 2 * m;
    float w[24];
#pragma unroll
    for (int q = 0; q < 12; q++) {
      float2 t2 = *(const float2*)&row[A0 + 2 * q];
      w[2 * q] = t2.x; w[2 * q + 1] = t2.y;
    }
#pragma unroll
    for (int i = 0; i < 16; i++) {
      acc[i] = fmaf(g4.x, w[7 + i], acc[i]);
      acc[i] = fmaf(g4.y, w[5 + i], acc[i]);
      acc[i] = fmaf(g4.z, w[3 + i], acc[i]);
      acc[i] = fmaf(g4.w, w[1 + i], acc[i]);
    }
  }
#pragma unroll
  for (int i = 0; i < 16; i++)
    acc[i] = fmaf(0.5f, row[512 + d0 + i], acc[i]);

  int t = t0 + tt;
  if (t < NT) {
    float* dst = &xf[(b * NT + t) * DET + d0];
#pragma unroll
    for (int i = 0; i < 16; i++) dst[i] = acc[i];
  }
}

// ---------------- Pairing: build padded quad rows ----------------
__global__ __launch_bounds__(256) void pair_kernel(const float* __restrict__ xf,
                                                   float4* __restrict__ xq) {
  int tp = blockIdx.x, b = blockIdx.y;
  int t = tp + 1, u = 179 - tp;
  const float* ft = xf + ((size_t)b * NT + t) * DET;
  const float* fu = xf + ((size_t)b * NT + u) * DET;
  float4* dst = xq + ((size_t)b * NPAIR + tp) * QROW;
  for (int i = threadIdx.x; i < QROW; i += 256) {
    int d = i - PADQ;
    int d1 = d + 1;
    float at = ((unsigned)d  < 512u) ? ft[d]  : 0.f;
    float au = ((unsigned)d  < 512u) ? fu[d]  : 0.f;
    float bt = ((unsigned)d1 < 512u) ? ft[d1] : 0.f;
    float bu = ((unsigned)d1 < 512u) ? fu[d1] : 0.f;
    dst[i] = make_float4(at, au, bt, bu);
  }
}

// ---------------- Backprojection v2 ----------------
// 1024 blocks: 8 x-tiles x 8 y-tiles (quadrant [0,256)^2) x 16 b.
// Thread owns 4 y-rows x 4 symmetric pixels. 89 angle-pairs, dbuf LDS quads.
__global__ __launch_bounds__(256, 4) void backproj_kernel(
    const float* __restrict__ xf, const float* __restrict__ xq_,
    const float* __restrict__ ws, float* __restrict__ out) {
  __shared__ float4 quads[2][QROW];
  int tid = threadIdx.x;
  int b   = blockIdx.y;
  int tx  = (blockIdx.x & 7) * 32;
  int ty  = (blockIdx.x >> 3) * 32;
  int lx = tid & 31, ly = tid >> 5;

  const float2* trigp = (const float2*)(ws + 512);
  const float4* xqb = (const float4*)xq_ + (size_t)b * NPAIR * QROW + tid;
  char* lwave = (char*)&quads[0][0] + (tid >> 6) * 1024;

  float p  = (float)(tx + lx) - 255.5f;
  float q0 = (float)(ty + ly) - 255.5f;

  float2 U[4], V[4], W[4], Z[4];
#pragma unroll
  for (int j = 0; j < 4; j++) {
    U[j] = make_float2(0.f, 0.f); V[j] = U[j]; W[j] = U[j]; Z[j] = U[j];
  }

  stage3(xqb, lwave);            // tp = 0 -> buf 0
  __syncthreads();

  for (int tp = 0; tp < NPAIR; tp++) {
    if (tp + 1 < NPAIR)
      stage3(xqb + (size_t)(tp + 1) * QROW, lwave + ((tp + 1) & 1) * (QROW * 16));
    float2 cs = trigp[tp];
    float c = cs.x, s = cs.y;
    const float2* colq2 = (const float2*)&quads[tp & 1][0];
    float inner = fmaf(-s, q0, 255.5f + (float)PADQ);
    float iyA = fmaf( c, p, inner);
    float iyB = fmaf(-c, p, inner);
    float s8 = 8.f * s;
#pragma unroll
    for (int j = 0; j < 4; j++) {
      int   iA = (int)iyA;
      float wA = iyA - (float)iA;
      int   iB = (int)iyB;
      float wB = iyB - (float)iB;
      float2 QAl = colq2[2 * iA],         QAh = colq2[2 * iA + 1];
      float2 QBl = colq2[2 * iB],         QBh = colq2[2 * iB + 1];
      float2 QCl = colq2[2 * (726 - iA)], QCh = colq2[2 * (726 - iA) + 1];
      float2 QDl = colq2[2 * (726 - iB)], QDh = colq2[2 * (726 - iB) + 1];
      float2 wa  = make_float2(wA, wA);
      float2 wa1 = make_float2(1.f - wA, 1.f - wA);
      float2 wb  = make_float2(wB, wB);
      float2 wb1 = make_float2(1.f - wB, 1.f - wB);
      U[j] = pk_fma2(wa1, QAl, U[j]);   // (P1@t, P2@u)
      U[j] = pk_fma2(wa , QAh, U[j]);
      V[j] = pk_fma2(wb1, QBl, V[j]);   // (P2@t, P1@u)
      V[j] = pk_fma2(wb , QBh, V[j]);
      W[j] = pk_fma2(wa , QCl, W[j]);   // (P3@t, P4@u)  weights swapped
      W[j] = pk_fma2(wa1, QCh, W[j]);
      Z[j] = pk_fma2(wb , QDl, Z[j]);   // (P4@t, P3@u)
      Z[j] = pk_fma2(wb1, QDh, Z[j]);
      iyA -= s8; iyB -= s8;
    }
    __syncthreads();
  }

  // singles t=0 (iy=X exactly) and t=90 (iy ~= 511-Y, err<2e-5), mask, scale
  const float* f0  = xf + (size_t)b * NT * DET;
  const float* f90 = f0 + 90 * DET;
  int X1 = tx + lx, X2 = 511 - X1;
  float g0a = f0[X1], g0b = f0[X2];
  int kx = 2 * X1 - 511;
  const float SC = (float)(PI_D / 360.0);
  float* ob = out + (size_t)b * DET * DET;
#pragma unroll
  for (int j = 0; j < 4; j++) {
    int Y1 = ty + ly + 8 * j, Y2 = 511 - Y1;
    float g90a = f90[Y2];    // col90[511-Y1] for P1,P2
    float g90b = f90[Y1];    // col90[511-Y2] for P3,P4
    int ky = 2 * Y1 - 511;
    bool in = (kx * kx + ky * ky) <= 261632;
    float P1 = U[j].x + V[j].y + g0a + g90a;
    float P2 = U[j].y + V[j].x + g0b + g90a;
    float P3 = W[j].x + Z[j].y + g0b + g90b;
    float P4 = W[j].y + Z[j].x + g0a + g90b;
    ob[(size_t)Y1 * DET + X1] = in ? P1 * SC : 0.f;
    ob[(size_t)Y1 * DET + X2] = in ? P2 * SC : 0.f;
    ob[(size_t)Y2 * DET + X2] = in ? P3 * SC : 0.f;
    ob[(size_t)Y2 * DET + X1] = in ? P4 * SC : 0.f;
  }
}

extern "C" void kernel_launch(void* const* d_in, const int* in_sizes, int n_in,
                              void* d_out, int out_size, void* d_ws, size_t ws_size,
                              hipStream_t stream) {
  (void)in_sizes; (void)n_in; (void)out_size; (void)ws_size;
  const float* x = (const float*)d_in[0];
  float* out = (float*)d_out;
  float* ws  = (float*)d_ws;
  float* xf  = (float*)((char*)d_ws + XF_OFF);
  float4* xq = (float4*)((char*)d_ws + XQ_OFF);

  setup_kernel<<<1, 512, 0, stream>>>(ws);
  filter_kernel<<<dim3(23, 16), 256, 0, stream>>>(x, ws, xf);
  pair_kernel<<<dim3(NPAIR, 16), 256, 0, stream>>>(xf, xq);
  backproj_kernel<<<dim3(64, 16), 256, 0, stream>>>(xf, (const float*)xq, ws, out);
}

// Round 3
// 211.302 us; speedup vs baseline: 1.3683x; 1.0374x over previous
//
#include <hip/hip_runtime.h>
#include <math.h>

#define DET 512
#define NB  16
#define NT  180
#define PI_D 3.14159265358979323846
#define NPAIR 89
#define PADQ 108
#define QROW 768                 // padded quads per (b,tp) row; 728 used
#define XF_OFF 8192
#define XQ_OFF (XF_OFF + NB*NT*DET*4)

// ws layout (bytes):
//   [0,2048)      godd[512]          odd-tap filter coefficients
//   [2048,2760)   trigp float2[89]   symmetric pair trig (c,s)
//   [XF_OFF,+5.9M)  xf[b][t][d]      filtered sinogram
//   [XQ_OFF,+17.9M) xq[b][tp][768]   float4 quads (gt[i],gu[i],gt[i+1],gu[i+1]), pad +-108

__device__ inline float2 pk_fma2(float2 a, float2 b, float2 c) {
  float2 d;
  asm("v_pk_fma_f32 %0, %1, %2, %3" : "=v"(d) : "v"(a), "v"(b), "v"(c));
  return d;
}

__device__ inline void stage3(const float4* g, char* l) {
#pragma unroll
  for (int c = 0; c < 3; c++)
    __builtin_amdgcn_global_load_lds(
        (const __attribute__((address_space(1))) unsigned int*)(g + c * 256),
        (__attribute__((address_space(3))) unsigned int*)(l + c * 4096),
        16, 0, 0);
}

__global__ __launch_bounds__(512) void setup_kernel(float* __restrict__ ws) {
  int tid = threadIdx.x;
  float*  godd  = ws;
  float2* trigp = (float2*)(ws + 512);
  if (tid < 512) {
    int o = 2 * tid - 511;
    double od = (double)o;
    godd[tid] = (float)(-2.0 / (PI_D * PI_D * od * od));
  }
  if (tid < NPAIR) {
    int t = tid + 1, u = 179 - tid;
    float rt = (float)t * (float)(PI_D / 180.0);
    float ru = (float)u * (float)(PI_D / 180.0);
    double ct = cos((double)rt), st = sin((double)rt);
    double cu = cos((double)ru), su = sin((double)ru);
    float2 cs;
    cs.x = (float)((ct - cu) * 0.5);
    cs.y = (float)((st + su) * 0.5);
    trigp[tid] = cs;
  }
}

// ---------------- Filter v3: sliding register window ----------------
// Grid (45,16): 4 t-columns/block, 256 thr = 4 cols x 64 strips of 8 outputs.
// Tap (m): xf[d] += g[m] * row[d + 1023 - 2m], row[512+k] = x[k], halos zero.
// 32-float register window W, logical base B_n = d0+1008-16n (m=8n),
// phys = (k + 16*(n&1)) & 31. Loads 4 float4/iter; taps via uniform SMEM reads.
#define FS 1540

__global__ __launch_bounds__(256) void filter_kernel(const float* __restrict__ x,
                                                     const float* __restrict__ gw,
                                                     float* __restrict__ xf) {
  __shared__ float lds[32 + 4 * FS + 16];
  float* xcp = lds + 32;          // 32-float guard below for spurious tail load
  int tid = threadIdx.x;
  int b   = blockIdx.y;
  int t0  = blockIdx.x * 4;       // 45*4 = 180 exactly

  for (int i = tid; i < 32 + 4 * FS + 16; i += 256) lds[i] = 0.f;
  __syncthreads();
  for (int k = tid; k < 512; k += 256) {
    const float4 v = *(const float4*)&x[((size_t)b * DET + k) * NT + t0];
    xcp[0 * FS + 512 + k] = v.x;
    xcp[1 * FS + 512 + k] = v.y;
    xcp[2 * FS + 512 + k] = v.z;
    xcp[3 * FS + 512 + k] = v.w;
  }
  __syncthreads();

  int tt = tid & 3;
  int d0 = (tid >> 2) * 8;
  const float* row = &xcp[tt * FS];

  float acc[8];
#pragma unroll
  for (int i = 0; i < 8; i++) acc[i] = 0.f;

  float W[32];
  {
    const float4* rq = (const float4*)(row + d0 + 1008);
#pragma unroll
    for (int c = 0; c < 8; c++) {
      float4 v = rq[c];
      W[4 * c + 0] = v.x; W[4 * c + 1] = v.y; W[4 * c + 2] = v.z; W[4 * c + 3] = v.w;
    }
  }

  auto body = [&](int n, int phi) {
    int m = 8 * n;
    float g[8];
#pragma unroll
    for (int r = 0; r < 8; r++) g[r] = gw[m + r];   // uniform -> scalar loads
#pragma unroll
    for (int r = 0; r < 8; r++) {
#pragma unroll
      for (int i = 0; i < 8; i++) {
        int k = 15 + i - 2 * r;                     // 1..29
        int ph = (k + 16 * phi) & 31;
        acc[i] = fmaf(g[r], W[ph], acc[i]);
      }
    }
    // load window half for iter n+1 into phys [16*(1-phi), +16)
    const float4* rq = (const float4*)(row + d0 + 1008 - 16 * (n + 1));
    int base = 16 * (1 - phi);
#pragma unroll
    for (int c = 0; c < 4; c++) {
      float4 v = rq[c];
      W[base + 4 * c + 0] = v.x; W[base + 4 * c + 1] = v.y;
      W[base + 4 * c + 2] = v.z; W[base + 4 * c + 3] = v.w;
    }
  };

  for (int n = 0; n < 64; n += 2) { body(n, 0); body(n + 1, 1); }

#pragma unroll
  for (int i = 0; i < 8; i++)
    acc[i] = fmaf(0.5f, row[512 + d0 + i], acc[i]);

  float* dst = &xf[((size_t)b * NT + t0 + tt) * DET + d0];
  *(float4*)dst       = make_float4(acc[0], acc[1], acc[2], acc[3]);
  *(float4*)(dst + 4) = make_float4(acc[4], acc[5], acc[6], acc[7]);
}

// ---------------- Pairing: build padded quad rows ----------------
__global__ __launch_bounds__(256) void pair_kernel(const float* __restrict__ xf,
                                                   float4* __restrict__ xq) {
  int tp = blockIdx.x, b = blockIdx.y;
  int t = tp + 1, u = 179 - tp;
  const float* ft = xf + ((size_t)b * NT + t) * DET;
  const float* fu = xf + ((size_t)b * NT + u) * DET;
  float4* dst = xq + ((size_t)b * NPAIR + tp) * QROW;
  for (int i = threadIdx.x; i < QROW; i += 256) {
    int d = i - PADQ;
    int d1 = d + 1;
    float at = ((unsigned)d  < 512u) ? ft[d]  : 0.f;
    float au = ((unsigned)d  < 512u) ? fu[d]  : 0.f;
    float bt = ((unsigned)d1 < 512u) ? ft[d1] : 0.f;
    float bu = ((unsigned)d1 < 512u) ? fu[d1] : 0.f;
    dst[i] = make_float4(at, au, bt, bu);
  }
}

// ---------------- Backprojection v3: + circle-mask skips ----------------
__global__ __launch_bounds__(256, 4) void backproj_kernel(
    const float* __restrict__ xf, const float* __restrict__ xq_,
    const float* __restrict__ ws, float* __restrict__ out) {
  __shared__ float4 quads[2][QROW];
  int tid = threadIdx.x;
  int b   = blockIdx.y;
  int tx  = (blockIdx.x & 7) * 32;
  int ty  = (blockIdx.x >> 3) * 32;
  int lx = tid & 31, ly = tid >> 5;

  float* ob = out + (size_t)b * DET * DET;
  int X1 = tx + lx, X2 = 511 - X1;

  // block-level skip: entire 32x32 quadrant tile (and its 3 mirrors) outside
  int mbx = 449 - 2 * tx, mby = 449 - 2 * ty;
  if (mbx * mbx + mby * mby > 261632) {
#pragma unroll
    for (int j = 0; j < 4; j++) {
      int Y1 = ty + ly + 8 * j, Y2 = 511 - Y1;
      ob[(size_t)Y1 * DET + X1] = 0.f;
      ob[(size_t)Y1 * DET + X2] = 0.f;
      ob[(size_t)Y2 * DET + X2] = 0.f;
      ob[(size_t)Y2 * DET + X1] = 0.f;
    }
    return;
  }

  const float2* trigp = (const float2*)(ws + 512);
  const float4* xqb = (const float4*)xq_ + (size_t)b * NPAIR * QROW + tid;
  char* lwave = (char*)&quads[0][0] + (tid >> 6) * 1024;

  float p  = (float)(tx + lx) - 255.5f;
  float q0 = (float)(ty + ly) - 255.5f;

  // per-(wave,j) liveness: skip j-rows where all 64 lanes are outside
  int wv = tid >> 6;
  int mkx = 449 - 2 * tx;
  bool live[4];
#pragma unroll
  for (int j = 0; j < 4; j++) {
    int mky = 509 - 2 * ty - 4 * wv - 16 * j;
    live[j] = (mkx * mkx + mky * mky <= 261632);
  }

  float2 U[4], V[4], W[4], Z[4];
#pragma unroll
  for (int j = 0; j < 4; j++) {
    U[j] = make_float2(0.f, 0.f); V[j] = U[j]; W[j] = U[j]; Z[j] = U[j];
  }

  stage3(xqb, lwave);            // tp = 0 -> buf 0
  __syncthreads();

  for (int tp = 0; tp < NPAIR; tp++) {
    if (tp + 1 < NPAIR)
      stage3(xqb + (size_t)(tp + 1) * QROW, lwave + ((tp + 1) & 1) * (QROW * 16));
    float2 cs = trigp[tp];
    float c = cs.x, s = cs.y;
    const float2* colq2 = (const float2*)&quads[tp & 1][0];
    float inner = fmaf(-s, q0, 255.5f + (float)PADQ);
    float iyA = fmaf( c, p, inner);
    float iyB = fmaf(-c, p, inner);
    float s8 = 8.f * s;
#pragma unroll
    for (int j = 0; j < 4; j++) {
      if (live[j]) {
        int   iA = (int)iyA;
        float wA = iyA - (float)iA;
        int   iB = (int)iyB;
        float wB = iyB - (float)iB;
        float2 QAl = colq2[2 * iA],         QAh = colq2[2 * iA + 1];
        float2 QBl = colq2[2 * iB],         QBh = colq2[2 * iB + 1];
        float2 QCl = colq2[2 * (726 - iA)], QCh = colq2[2 * (726 - iA) + 1];
        float2 QDl = colq2[2 * (726 - iB)], QDh = colq2[2 * (726 - iB) + 1];
        float2 wa  = make_float2(wA, wA);
        float2 wa1 = make_float2(1.f - wA, 1.f - wA);
        float2 wb  = make_float2(wB, wB);
        float2 wb1 = make_float2(1.f - wB, 1.f - wB);
        U[j] = pk_fma2(wa1, QAl, U[j]);
        U[j] = pk_fma2(wa , QAh, U[j]);
        V[j] = pk_fma2(wb1, QBl, V[j]);
        V[j] = pk_fma2(wb , QBh, V[j]);
        W[j] = pk_fma2(wa , QCl, W[j]);
        W[j] = pk_fma2(wa1, QCh, W[j]);
        Z[j] = pk_fma2(wb , QDl, Z[j]);
        Z[j] = pk_fma2(wb1, QDh, Z[j]);
      }
      iyA -= s8; iyB -= s8;
    }
    __syncthreads();
  }

  const float* f0  = xf + (size_t)b * NT * DET;
  const float* f90 = f0 + 90 * DET;
  float g0a = f0[X1], g0b = f0[X2];
  int kx = 2 * X1 - 511;
  const float SC = (float)(PI_D / 360.0);
#pragma unroll
  for (int j = 0; j < 4; j++) {
    int Y1 = ty + ly + 8 * j, Y2 = 511 - Y1;
    float g90a = f90[Y2];
    float g90b = f90[Y1];
    int ky = 2 * Y1 - 511;
    bool in = (kx * kx + ky * ky) <= 261632;
    float P1 = U[j].x + V[j].y + g0a + g90a;
    float P2 = U[j].y + V[j].x + g0b + g90a;
    float P3 = W[j].x + Z[j].y + g0b + g90b;
    float P4 = W[j].y + Z[j].x + g0a + g90b;
    ob[(size_t)Y1 * DET + X1] = in ? P1 * SC : 0.f;
    ob[(size_t)Y1 * DET + X2] = in ? P2 * SC : 0.f;
    ob[(size_t)Y2 * DET + X2] = in ? P3 * SC : 0.f;
    ob[(size_t)Y2 * DET + X1] = in ? P4 * SC : 0.f;
  }
}

extern "C" void kernel_launch(void* const* d_in, const int* in_sizes, int n_in,
                              void* d_out, int out_size, void* d_ws, size_t ws_size,
                              hipStream_t stream) {
  (void)in_sizes; (void)n_in; (void)out_size; (void)ws_size;
  const float* x = (const float*)d_in[0];
  float* out = (float*)d_out;
  float* ws  = (float*)d_ws;
  float* xf  = (float*)((char*)d_ws + XF_OFF);
  float4* xq = (float4*)((char*)d_ws + XQ_OFF);

  setup_kernel<<<1, 512, 0, stream>>>(ws);
  filter_kernel<<<dim3(45, 16), 256, 0, stream>>>(x, ws, xf);
  pair_kernel<<<dim3(NPAIR, 16), 256, 0, stream>>>(xf, xq);
  backproj_kernel<<<dim3(64, 16), 256, 0, stream>>>(xf, (const float*)xq, ws, out);
}

// Round 5
// 196.148 us; speedup vs baseline: 1.4740x; 1.0773x over previous
//
#include <hip/hip_runtime.h>
#include <math.h>

#define DET 512
#define NB  16
#define NT  180
#define PI_D 3.14159265358979323846
#define NPAIR 89
#define PADQ 108
#define QROW 768                 // padded quads per (b,tp) row; 728 used

// ws layout (bytes):
//   [0,712)          trigp float2[89]  symmetric pair trig (c,s)
//   [4096,+32K)      xf0[b][512]       filtered row t=0
//   [36864,+32K)     xf90[b][512]      filtered row t=90
//   [131072,+17.5M)  xq[b][tp][768]    float4 quads (gt[i],gu[i],gt[i+1],gu[i+1]), pad +-108
#define XF0_OFF  4096
#define XF90_OFF 36864
#define XQ_OFF   131072

// ---- compile-time ramp-filter taps (odd offsets o=2m-511): -2/(pi*o)^2 ----
struct Taps { float v[512]; };
static constexpr Taps mk_taps() {
  Taps t{};
  for (int m = 0; m < 512; ++m) {
    double o = (double)(2 * m - 511);
    t.v[m] = (float)(-2.0 / (PI_D * PI_D * o * o));
  }
  return t;
}
__constant__ Taps GODD = mk_taps();

__device__ inline float2 pk_fma2(float2 a, float2 b, float2 c) {
  // packed fp32 FMA: all three sources must be 64b-aligned VGPR pairs
  float2 d;
  asm("v_pk_fma_f32 %0, %1, %2, %3" : "=v"(d) : "v"(a), "v"(b), "v"(c));
  return d;
}

__device__ inline void stage3(const float4* g, char* l) {
#pragma unroll
  for (int c = 0; c < 3; c++)
    __builtin_amdgcn_global_load_lds(
        (const __attribute__((address_space(1))) unsigned int*)(g + c * 256),
        (__attribute__((address_space(3))) unsigned int*)(l + c * 4096),
        16, 0, 0);
}

__global__ __launch_bounds__(256) void setup_kernel(float* __restrict__ ws) {
  int tid = threadIdx.x;
  float2* trigp = (float2*)ws;
  if (tid < NPAIR) {
    int t = tid + 1, u = 179 - tid;
    float rt = (float)t * (float)(PI_D / 180.0);
    float ru = (float)u * (float)(PI_D / 180.0);
    double ct = cos((double)rt), st = sin((double)rt);
    double cu = cos((double)ru), su = sin((double)ru);
    float2 cs;
    cs.x = (float)((ct - cu) * 0.5);
    cs.y = (float)((st + su) * 0.5);
    trigp[tid] = cs;
  }
}

// ---------------- Fused filter + pairing ----------------
// Grid (45,16). Block p<44 handles angles {2p+1, 2p+2, 178-2p, 179-2p}
// = pairs tp=2p (cols 0,3) and tp=2p+1 (cols 1,2). Block 44: {89,0,90,91}
// = pair tp=88 (cols 0,3) + singles t=0 (col1), t=90 (col2).
// Conv: 64 d-strips x 8 outputs, 32-float register window slid 16/iter,
// taps from __constant__ (scalar loads), prefetched one iter ahead.
#define FS 1540

template <int PHI>
__device__ __forceinline__ void conv_step(int n, const float* row, int d0,
                                          float (&Wn)[32], float (&acc)[8],
                                          float (&gcur)[8], float (&gnext)[8]) {
  if (n < 63) {
#pragma unroll
    for (int r = 0; r < 8; r++) gnext[r] = GODD.v[8 * (n + 1) + r];
  }
#pragma unroll
  for (int r = 0; r < 8; r++) {
#pragma unroll
    for (int i = 0; i < 8; i++) {
      int kk = 15 + i - 2 * r;               // 1..22
      int ph = (kk + 16 * PHI) & 31;         // compile-time
      acc[i] = fmaf(gcur[r], Wn[ph], acc[i]);
    }
  }
  const float4* rq = (const float4*)(row + d0 + 1008 - 16 * (n + 1));
  constexpr int base = 16 * (1 - PHI);
#pragma unroll
  for (int c = 0; c < 4; c++) {
    float4 v = rq[c];
    Wn[base + 4 * c + 0] = v.x; Wn[base + 4 * c + 1] = v.y;
    Wn[base + 4 * c + 2] = v.z; Wn[base + 4 * c + 3] = v.w;
  }
}

__global__ __launch_bounds__(256) void filter_kernel(const float* __restrict__ x,
                                                     float* __restrict__ ws) {
  __shared__ float lds[32 + 4 * FS + 16];
  float* xcp = lds + 32;          // 32-float guard below for final-iter tail load
  int tid = threadIdx.x;
  int b   = blockIdx.y;
  int p   = blockIdx.x;

  int a0, a1, a2, a3;
  if (p < 44) { a0 = 2*p+1; a1 = 2*p+2; a2 = 178-2*p; a3 = 179-2*p; }
  else        { a0 = 89;    a1 = 0;     a2 = 90;      a3 = 91;      }

  for (int i = tid; i < 32 + 4 * FS + 16; i += 256) lds[i] = 0.f;
  __syncthreads();
  for (int k = tid; k < 512; k += 256) {
    const float* xr = &x[((size_t)b * DET + k) * NT];
    xcp[0 * FS + 512 + k] = xr[a0];
    xcp[1 * FS + 512 + k] = xr[a1];
    xcp[2 * FS + 512 + k] = xr[a2];
    xcp[3 * FS + 512 + k] = xr[a3];
  }
  __syncthreads();

  int tt = tid & 3;
  int d0 = (tid >> 2) * 8;
  const float* row = &xcp[tt * FS];

  float acc[8];
#pragma unroll
  for (int i = 0; i < 8; i++) acc[i] = 0.f;

  float Wn[32];
  {
    const float4* rq = (const float4*)(row + d0 + 1008);
#pragma unroll
    for (int c = 0; c < 8; c++) {
      float4 v = rq[c];
      Wn[4*c+0] = v.x; Wn[4*c+1] = v.y; Wn[4*c+2] = v.z; Wn[4*c+3] = v.w;
    }
  }
  float ga[8], gb[8];
#pragma unroll
  for (int r = 0; r < 8; r++) ga[r] = GODD.v[r];

  for (int n = 0; n < 64; n += 2) {
    conv_step<0>(n,     row, d0, Wn, acc, ga, gb);
    conv_step<1>(n + 1, row, d0, Wn, acc, gb, ga);
  }
#pragma unroll
  for (int i = 0; i < 8; i++)
    acc[i] = fmaf(0.5f, row[512 + d0 + i], acc[i]);

  // stash columns back to LDS (low-halo region, conv reads are done)
  __syncthreads();
  {
    float* cst = &xcp[tt * FS];
#pragma unroll
    for (int i = 0; i < 8; i++) cst[d0 + i] = acc[i];
  }
  __syncthreads();

  // assemble quad rows for the block's pairs
  float4* xqB = (float4*)((char*)ws + XQ_OFF) + (size_t)b * NPAIR * QROW;
  int tp0 = (p < 44) ? 2 * p : 88;
  {
    const float* ct = &xcp[0 * FS];
    const float* cu = &xcp[3 * FS];
    float4* dst = xqB + (size_t)tp0 * QROW;
    for (int i = tid; i < QROW; i += 256) {
      int d = i - PADQ, d1 = d + 1;
      float va = ((unsigned)d  < 512u) ? ct[d]  : 0.f;
      float vb = ((unsigned)d  < 512u) ? cu[d]  : 0.f;
      float vc = ((unsigned)d1 < 512u) ? ct[d1] : 0.f;
      float vd = ((unsigned)d1 < 512u) ? cu[d1] : 0.f;
      dst[i] = make_float4(va, vb, vc, vd);
    }
  }
  if (p < 44) {
    const float* ct = &xcp[1 * FS];
    const float* cu = &xcp[2 * FS];
    float4* dst = xqB + (size_t)(2 * p + 1) * QROW;
    for (int i = tid; i < QROW; i += 256) {
      int d = i - PADQ, d1 = d + 1;
      float va = ((unsigned)d  < 512u) ? ct[d]  : 0.f;
      float vb = ((unsigned)d  < 512u) ? cu[d]  : 0.f;
      float vc = ((unsigned)d1 < 512u) ? ct[d1] : 0.f;
      float vd = ((unsigned)d1 < 512u) ? cu[d1] : 0.f;
      dst[i] = make_float4(va, vb, vc, vd);
    }
  } else {
    // singles: raw filtered rows t=0 (col1), t=90 (col2)
    float* f0  = (float*)((char*)ws + XF0_OFF)  + (size_t)b * DET;
    float* f90 = (float*)((char*)ws + XF90_OFF) + (size_t)b * DET;
    for (int i = tid; i < 512; i += 256) {
      f0[i]  = xcp[1 * FS + i];
      f90[i] = xcp[2 * FS + i];
    }
  }
}

// ---------------- Backprojection v4: b128 gathers ----------------
__global__ __launch_bounds__(256, 4) void backproj_kernel(
    const float* __restrict__ ws, float* __restrict__ out) {
  __shared__ float4 quads[2][QROW];
  int tid = threadIdx.x;
  int b   = blockIdx.y;
  int tx  = (blockIdx.x & 7) * 32;
  int ty  = (blockIdx.x >> 3) * 32;
  int lx = tid & 31, ly = tid >> 5;

  float* ob = out + (size_t)b * DET * DET;
  int X1 = tx + lx, X2 = 511 - X1;

  // block-level skip: entire 32x32 quadrant tile (and its 3 mirrors) outside
  int mbx = 449 - 2 * tx, mby = 449 - 2 * ty;
  if (mbx * mbx + mby * mby > 261632) {
#pragma unroll
    for (int j = 0; j < 4; j++) {
      int Y1 = ty + ly + 8 * j, Y2 = 511 - Y1;
      ob[(size_t)Y1 * DET + X1] = 0.f;
      ob[(size_t)Y1 * DET + X2] = 0.f;
      ob[(size_t)Y2 * DET + X2] = 0.f;
      ob[(size_t)Y2 * DET + X1] = 0.f;
    }
    return;
  }

  const float2* trigp = (const float2*)ws;
  const float4* xqb = (const float4*)((const char*)ws + XQ_OFF)
                      + (size_t)b * NPAIR * QROW + tid;
  char* lwave = (char*)&quads[0][0] + (tid >> 6) * 1024;

  float p  = (float)(tx + lx) - 255.5f;
  float q0 = (float)(ty + ly) - 255.5f;

  // per-(wave,j) liveness: skip j-rows where all 64 lanes are outside
  int wv = tid >> 6;
  int mkx = 449 - 2 * tx;
  bool live[4];
#pragma unroll
  for (int j = 0; j < 4; j++) {
    int mky = 509 - 2 * ty - 4 * wv - 16 * j;
    live[j] = (mkx * mkx + mky * mky <= 261632);
  }

  float2 U[4], V[4], W[4], Z[4];
#pragma unroll
  for (int j = 0; j < 4; j++) {
    U[j] = make_float2(0.f, 0.f); V[j] = U[j]; W[j] = U[j]; Z[j] = U[j];
  }

  stage3(xqb, lwave);            // tp = 0 -> buf 0
  __syncthreads();

  for (int tp = 0; tp < NPAIR; tp++) {
    if (tp + 1 < NPAIR)
      stage3(xqb + (size_t)(tp + 1) * QROW, lwave + ((tp + 1) & 1) * (QROW * 16));
    float2 cs = trigp[tp];
    float c = cs.x, s = cs.y;
    const float4* colq4 = &quads[tp & 1][0];
    float inner = fmaf(-s, q0, 255.5f + (float)PADQ);
    float iyA = fmaf( c, p, inner);
    float iyB = fmaf(-c, p, inner);
    float s8 = 8.f * s;
#pragma unroll
    for (int j = 0; j < 4; j++) {
      if (live[j]) {
        int   iA = (int)iyA;          // iy in [1.5,726] -> trunc == floor
        float wA = iyA - (float)iA;
        int   iB = (int)iyB;
        float wB = iyB - (float)iB;
        float4 QA = colq4[iA];
        float4 QB = colq4[iB];
        float4 QC = colq4[726 - iA];
        float4 QD = colq4[726 - iB];
        float2 wa  = make_float2(wA, wA);
        float2 wa1 = make_float2(1.f - wA, 1.f - wA);
        float2 wb  = make_float2(wB, wB);
        float2 wb1 = make_float2(1.f - wB, 1.f - wB);
        U[j] = pk_fma2(wa1, make_float2(QA.x, QA.y), U[j]);   // (P1@t,P2@u)
        U[j] = pk_fma2(wa , make_float2(QA.z, QA.w), U[j]);
        V[j] = pk_fma2(wb1, make_float2(QB.x, QB.y), V[j]);   // (P2@t,P1@u)
        V[j] = pk_fma2(wb , make_float2(QB.z, QB.w), V[j]);
        W[j] = pk_fma2(wa , make_float2(QC.x, QC.y), W[j]);   // (P3@t,P4@u)
        W[j] = pk_fma2(wa1, make_float2(QC.z, QC.w), W[j]);
        Z[j] = pk_fma2(wb , make_float2(QD.x, QD.y), Z[j]);   // (P4@t,P3@u)
        Z[j] = pk_fma2(wb1, make_float2(QD.z, QD.w), Z[j]);
      }
      iyA -= s8; iyB -= s8;
    }
    __syncthreads();
  }

  const float* f0  = (const float*)((const char*)ws + XF0_OFF)  + (size_t)b * DET;
  const float* f90 = (const float*)((const char*)ws + XF90_OFF) + (size_t)b * DET;
  float g0a = f0[X1], g0b = f0[X2];
  int kx = 2 * X1 - 511;
  const float SC = (float)(PI_D / 360.0);
#pragma unroll
  for (int j = 0; j < 4; j++) {
    int Y1 = ty + ly + 8 * j, Y2 = 511 - Y1;
    float g90a = f90[Y2];
    float g90b = f90[Y1];
    int ky = 2 * Y1 - 511;
    bool in = (kx * kx + ky * ky) <= 261632;
    float P1 = U[j].x + V[j].y + g0a + g90a;
    float P2 = U[j].y + V[j].x + g0b + g90a;
    float P3 = W[j].x + Z[j].y + g0b + g90b;
    float P4 = W[j].y + Z[j].x + g0a + g90b;
    ob[(size_t)Y1 * DET + X1] = in ? P1 * SC : 0.f;
    ob[(size_t)Y1 * DET + X2] = in ? P2 * SC : 0.f;
    ob[(size_t)Y2 * DET + X2] = in ? P3 * SC : 0.f;
    ob[(size_t)Y2 * DET + X1] = in ? P4 * SC : 0.f;
  }
}

extern "C" void kernel_launch(void* const* d_in, const int* in_sizes, int n_in,
                              void* d_out, int out_size, void* d_ws, size_t ws_size,
                              hipStream_t stream) {
  (void)in_sizes; (void)n_in; (void)out_size; (void)ws_size;
  const float* x = (const float*)d_in[0];
  float* out = (float*)d_out;
  float* ws  = (float*)d_ws;

  setup_kernel<<<1, 256, 0, stream>>>(ws);
  filter_kernel<<<dim3(45, 16), 256, 0, stream>>>(x, ws);
  backproj_kernel<<<dim3(64, 16), 256, 0, stream>>>(ws, out);
}